// Round 2
// baseline (499.874 us; speedup 1.0000x reference)
//
#include <hip/hip_runtime.h>

typedef __attribute__((ext_vector_type(4))) float f32x4;
typedef __attribute__((ext_vector_type(8))) short bf16x8;

constexpr int NB = 16, NN = 2048, NS = 4, NDIM = 512, NH = 8, NDS = 64;
constexpr float LOG2PI = 1.8378770664093453f;
constexpr float INV_SQRT_DIM = 0.04419417382415922f;  // 1/sqrt(512)

__device__ inline short f2bf(float f) {
  union { float f; unsigned u; } v; v.f = f;
  unsigned r = v.u + 0x7FFFu + ((v.u >> 16) & 1u);  // RNE
  return (short)(r >> 16);
}
__device__ inline float bf2f(short b) {
  union { unsigned u; float f; } v;
  v.u = ((unsigned)(unsigned short)b) << 16;
  return v.f;
}

// ---------------------------------------------------------------------------
// Projection GEMM: C[r, j] = sum_i X[r, i] * W[j, i] + bias[j]
//   rows r = (b*2048 + n)*4 + s  (131072 rows), cols j = 0..511
// WHICH==0: epilogue reduces GMM log-likelihood per (row, head) -> ll_ws
// WHICH==1: epilogue writes V as bf16 to v_ws in [g=(b*4+s)*8+h][n][d] layout
// Tile: 128x128, BK=64, 4 waves (2x2), wave tile 64x64 (= exactly one head wide)
// ---------------------------------------------------------------------------
template<int WHICH>
__global__ __launch_bounds__(256) void proj_kernel(
    const float* __restrict__ X, const float* __restrict__ W,
    const float* __restrict__ bias, const float* __restrict__ Mp,
    const float* __restrict__ Sp, const float* __restrict__ pp,
    float* __restrict__ ll_ws, short* __restrict__ v_ws)
{
  constexpr int LDT = 72;  // LDS row stride (bf16 elems): 144B, 16B-aligned
  __shared__ short As[128 * LDT];
  __shared__ short Bs[128 * LDT];

  const int bid = blockIdx.x;
  const int ct = bid & 3;        // col tile 0..3
  const int mt = bid >> 2;       // row tile 0..1023
  const int m0 = mt * 128;
  const int c0 = ct * 128;
  const int t = threadIdx.x;
  const int l = t & 63;
  const int w = t >> 6;
  const int wr = w >> 1, wc = w & 1;
  const int lg = l >> 4, lr = l & 15;

  f32x4 acc[4][4] = {};

  const int srr = t >> 4;        // staging row within 16-row pass
  const int skv = t & 15;        // float4 index within 64-float k-slice

  for (int k0 = 0; k0 < NDIM; k0 += 64) {
    #pragma unroll
    for (int pass = 0; pass < 8; ++pass) {
      const int row = pass * 16 + srr;
      const float4 xa = *reinterpret_cast<const float4*>(
          &X[(size_t)(m0 + row) * NDIM + k0 + skv * 4]);
      const float4 wb = *reinterpret_cast<const float4*>(
          &W[(size_t)(c0 + row) * NDIM + k0 + skv * 4]);
      short4 a4, b4;
      a4.x = f2bf(xa.x); a4.y = f2bf(xa.y); a4.z = f2bf(xa.z); a4.w = f2bf(xa.w);
      b4.x = f2bf(wb.x); b4.y = f2bf(wb.y); b4.z = f2bf(wb.z); b4.w = f2bf(wb.w);
      *reinterpret_cast<short4*>(&As[row * LDT + skv * 4]) = a4;
      *reinterpret_cast<short4*>(&Bs[row * LDT + skv * 4]) = b4;
    }
    __syncthreads();
    #pragma unroll
    for (int kk = 0; kk < 64; kk += 32) {
      bf16x8 a[4], b[4];
      #pragma unroll
      for (int i = 0; i < 4; ++i)
        a[i] = *reinterpret_cast<const bf16x8*>(
            &As[(wr * 64 + i * 16 + lr) * LDT + kk + lg * 8]);
      #pragma unroll
      for (int j = 0; j < 4; ++j)
        b[j] = *reinterpret_cast<const bf16x8*>(
            &Bs[(wc * 64 + j * 16 + lr) * LDT + kk + lg * 8]);
      #pragma unroll
      for (int i = 0; i < 4; ++i) {
        #pragma unroll
        for (int j = 0; j < 4; ++j)
          acc[i][j] = __builtin_amdgcn_mfma_f32_16x16x32_bf16(a[i], b[j], acc[i][j], 0, 0, 0);
      }
    }
    __syncthreads();
  }

  // C/D frag mapping: col = lane&15 (lr), row = 4*(lane>>4) + e within each 16-block.
  // Global row R = m0 + wr*64 + i*16 + 4*lg + e  -> base is a multiple of 4, so seed s == e.
  if (WHICH == 0) {
    const float p0 = pp[0], p1 = pp[1], p2 = pp[2], p3 = pp[3];
    const float pmx = fmaxf(fmaxf(p0, p1), fmaxf(p2, p3));
    const float lse = pmx + logf(expf(p0 - pmx) + expf(p1 - pmx) + expf(p2 - pmx) + expf(p3 - pmx));
    const float lp[4] = {p0 - lse, p1 - lse, p2 - lse, p3 - lse};

    float part[4][4];
    #pragma unroll
    for (int i = 0; i < 4; ++i)
      #pragma unroll
      for (int e = 0; e < 4; ++e) part[i][e] = 0.f;

    #pragma unroll
    for (int j = 0; j < 4; ++j) {
      const int Jg = c0 + wc * 64 + j * 16 + lr;
      const float bj = bias[Jg];
      #pragma unroll
      for (int e = 0; e < 4; ++e) {
        const float sv = Sp[e * NDIM + Jg];
        const float sig = log1pf(expf(sv));       // softplus
        const float mu = Mp[e * NDIM + Jg];
        const float cc = -0.5f * LOG2PI - logf(sig);
        const float i2 = 0.5f / (sig * sig);
        #pragma unroll
        for (int i = 0; i < 4; ++i) {
          const float kv = acc[i][j][e] + bj;
          const float d = kv - mu;
          part[i][e] += cc - d * d * i2;
        }
      }
    }
    // reduce over the head's 16 lane-columns (4 j-frags already summed in-register)
    #pragma unroll
    for (int off = 1; off < 16; off <<= 1) {
      #pragma unroll
      for (int i = 0; i < 4; ++i)
        #pragma unroll
        for (int e = 0; e < 4; ++e)
          part[i][e] += __shfl_xor(part[i][e], off, 64);
    }
    if (lr == 0) {
      const int h = ct * 2 + wc;
      #pragma unroll
      for (int i = 0; i < 4; ++i) {
        #pragma unroll
        for (int e = 0; e < 4; ++e) {
          const int R = m0 + wr * 64 + i * 16 + 4 * lg + e;
          const int bn = R >> 2;               // b*2048 + n
          const int bb = bn >> 11;
          const int nn = bn & (NN - 1);
          ll_ws[((size_t)((bb * NS + e) * NH + h)) * NN + nn] =
              (part[i][e] + lp[e]) * INV_SQRT_DIM;
        }
      }
    }
  } else {
    #pragma unroll
    for (int j = 0; j < 4; ++j) {
      const int Jg = c0 + wc * 64 + j * 16 + lr;
      const float bj = bias[Jg];
      const int h = Jg >> 6;
      const int d = Jg & 63;
      #pragma unroll
      for (int i = 0; i < 4; ++i) {
        #pragma unroll
        for (int e = 0; e < 4; ++e) {
          const int R = m0 + wr * 64 + i * 16 + 4 * lg + e;
          const int bn = R >> 2;
          const int bb = bn >> 11;
          const int nn = bn & (NN - 1);
          v_ws[((size_t)((bb * NS + e) * NH + h) * NN + nn) * NDS + d] =
              f2bf(acc[i][j][e] + bj);
        }
      }
    }
  }
}

// ---------------------------------------------------------------------------
// Pooling: per g=(b*4+s)*8+h : A = softmax(ll[g,:]), O0[g,d] = mu + sum_n A_n V[g,n,d]
// ---------------------------------------------------------------------------
__global__ __launch_bounds__(256) void pool_kernel(
    const float* __restrict__ ll_ws, const short* __restrict__ v_ws,
    const float* __restrict__ Mp, float* __restrict__ O0)
{
  __shared__ float Al[NN];
  __shared__ float red[4][NDS];
  __shared__ float sred[8];
  const int g = blockIdx.x;
  const int t = threadIdx.x;
  const int w = t >> 6, l = t & 63;
  const float* ll = ll_ws + (size_t)g * NN;

  float v8[8];
  float mx = -1e30f;
  #pragma unroll
  for (int i = 0; i < 8; ++i) { v8[i] = ll[t + i * 256]; mx = fmaxf(mx, v8[i]); }
  #pragma unroll
  for (int off = 1; off < 64; off <<= 1) mx = fmaxf(mx, __shfl_xor(mx, off, 64));
  if (l == 0) sred[w] = mx;
  __syncthreads();
  mx = fmaxf(fmaxf(sred[0], sred[1]), fmaxf(sred[2], sred[3]));

  float sum = 0.f;
  #pragma unroll
  for (int i = 0; i < 8; ++i) {
    const float e = expf(v8[i] - mx);
    Al[t + i * 256] = e;
    sum += e;
  }
  #pragma unroll
  for (int off = 1; off < 64; off <<= 1) sum += __shfl_xor(sum, off, 64);
  __syncthreads();
  if (l == 0) sred[4 + w] = sum;
  __syncthreads();
  const float lsum = sred[4] + sred[5] + sred[6] + sred[7];

  const short* vp = v_ws + (size_t)g * ((size_t)NN * NDS) + l;
  float acc = 0.f;
  #pragma unroll 8
  for (int i = 0; i < 512; ++i) {
    const int n = (w << 9) + i;
    acc += Al[n] * bf2f(vp[(size_t)n * NDS]);
  }
  red[w][l] = acc;
  __syncthreads();
  if (w == 0) {
    const float tot = red[0][l] + red[1][l] + red[2][l] + red[3][l];
    const int s = (g >> 3) & 3, h = g & 7;
    O0[(size_t)g * NDS + l] = Mp[s * NDIM + h * NDS + l] + tot / lsum;
  }
}

// ---------------------------------------------------------------------------
// BatchNorm1d (training mode, biased var, eps=1e-5) over B=16 per feature f.
// ---------------------------------------------------------------------------
__global__ __launch_bounds__(256) void bn_kernel(
    const float* __restrict__ Xin, const float* __restrict__ gg,
    const float* __restrict__ bb, float* __restrict__ Yo)
{
  const int f = blockIdx.x * 256 + threadIdx.x;  // 0..2047
  float x[NB];
  float m = 0.f;
  #pragma unroll
  for (int b = 0; b < NB; ++b) { x[b] = Xin[b * (NS * NDIM) + f]; m += x[b]; }
  m *= (1.f / NB);
  float v = 0.f;
  #pragma unroll
  for (int b = 0; b < NB; ++b) { const float d = x[b] - m; v += d * d; }
  v *= (1.f / NB);
  const float inv = rsqrtf(v + 1e-5f) * gg[f];
  const float bf = bb[f];
  #pragma unroll
  for (int b = 0; b < NB; ++b) Yo[b * (NS * NDIM) + f] = (x[b] - m) * inv + bf;
}

// ---------------------------------------------------------------------------
// Z = Y + relu(Y @ Wo^T + bo), rows = 64, cols = 512
// ---------------------------------------------------------------------------
__global__ __launch_bounds__(256) void mlp_kernel(
    const float* __restrict__ Yi, const float* __restrict__ Wo,
    const float* __restrict__ bo, float* __restrict__ Zo)
{
  const int idx = blockIdx.x * 256 + threadIdx.x;  // 0..32767
  const int r = idx >> 9, j = idx & 511;
  const float4* yr = reinterpret_cast<const float4*>(Yi + (size_t)r * NDIM);
  const float4* wrow = reinterpret_cast<const float4*>(Wo + (size_t)j * NDIM);
  float acc = 0.f;
  #pragma unroll 4
  for (int i = 0; i < NDIM / 4; ++i) {
    const float4 a = yr[i], b = wrow[i];
    acc += a.x * b.x + a.y * b.y + a.z * b.z + a.w * b.w;
  }
  const float rl = acc + bo[j];
  Zo[idx] = Yi[idx] + fmaxf(rl, 0.f);
}

extern "C" void kernel_launch(void* const* d_in, const int* in_sizes, int n_in,
                              void* d_out, int out_size, void* d_ws, size_t ws_size,
                              hipStream_t stream) {
  (void)in_sizes; (void)n_in; (void)out_size; (void)ws_size;
  const float* X  = (const float*)d_in[0];
  const float* M  = (const float*)d_in[1];
  const float* S  = (const float*)d_in[2];
  const float* p  = (const float*)d_in[3];
  const float* Wk = (const float*)d_in[4];
  const float* bk = (const float*)d_in[5];
  const float* Wv = (const float*)d_in[6];
  const float* bv = (const float*)d_in[7];
  const float* Wo = (const float*)d_in[8];
  const float* bo = (const float*)d_in[9];
  const float* g0 = (const float*)d_in[10];
  const float* b0 = (const float*)d_in[11];
  const float* g1 = (const float*)d_in[12];
  const float* b1 = (const float*)d_in[13];

  char* ws = (char*)d_ws;
  short* v_ws  = (short*)ws;                                    // 128 MiB bf16 V
  float* ll_ws = (float*)(ws + (size_t)134217728);              // 4 MiB logits
  float* O0    = (float*)(ws + (size_t)134217728 + 4194304);    // 128 KiB
  float* Y     = O0 + 32768;                                    // 128 KiB
  float* Z     = Y + 32768;                                     // 128 KiB

  hipLaunchKernelGGL((proj_kernel<0>), dim3(4096), dim3(256), 0, stream,
                     X, Wk, bk, M, S, p, ll_ws, v_ws);
  hipLaunchKernelGGL((proj_kernel<1>), dim3(4096), dim3(256), 0, stream,
                     X, Wv, bv, M, S, p, ll_ws, v_ws);
  pool_kernel<<<512, 256, 0, stream>>>(ll_ws, v_ws, M, O0);
  bn_kernel<<<8, 256, 0, stream>>>(O0, g0, b0, Y);
  mlp_kernel<<<128, 256, 0, stream>>>(Y, Wo, bo, Z);
  bn_kernel<<<8, 256, 0, stream>>>(Z, g1, b1, (float*)d_out);
}